// Round 3
// baseline (870.825 us; speedup 1.0000x reference)
//
#include <hip/hip_runtime.h>

#define HH 512
#define WW 512
#define RR 5
#define KS 11
#define EPS_F 1e-5f
#define NLOG2E 1.44269504088896340736f
#define ROWS 8   // output rows per thread

// One thread computes an 8-row output column for all 3 channels.
// Neighbor window: 18 rows x 11 cols, shared across the 8 outputs.
// Weight factorization: k(i,j) = t^{i^2} * t^{j^2}, t = exp(-1/(2w^2+eps))
// computed once per NEIGHBOR (exp2+rcp), taps cost 1 mul + 4 FMA each.
// CRITICAL codegen constraint (R2 lesson): accumulator arrays must only be
// indexed by compile-time constants -> inner o-loop has constant bounds with
// a constexpr guard, so it fully unrolls and arrays live in VGPRs.
__global__ __launch_bounds__(256, 2) void gauss_psf_kernel(const float* __restrict__ image,
                                                           const float* __restrict__ psf,
                                                           float* __restrict__ out) {
    const int x  = blockIdx.x * 64 + threadIdx.x;             // blockDim (64,4)
    const int y0 = (blockIdx.y * 4 + threadIdx.y) * ROWS;     // block covers 32 rows
    const int b  = blockIdx.z;

    const float* img0 = image + (size_t)b * 3 * HH * WW;
    const float* img1 = img0 + HH * WW;
    const float* img2 = img0 + 2 * HH * WW;
    const float* pw   = psf + (size_t)b * HH * WW;
    float*       outb = out + (size_t)b * 3 * HH * WW;

    // Per-column clamped x-index and 0/1 mask, hoisted (11 regs each).
    int   nxc[KS];
    float colf[KS];
#pragma unroll
    for (int j = 0; j < KS; ++j) {
        const int nx = x + j - RR;
        nxc[j]  = nx < 0 ? 0 : (nx > WW - 1 ? WW - 1 : nx);
        colf[j] = ((unsigned)nx < (unsigned)WW) ? 1.0f : 0.0f;
    }

    float o0[ROWS], o1[ROWS], o2[ROWS], ws[ROWS];
#pragma unroll
    for (int o = 0; o < ROWS; ++o) { o0[o] = o1[o] = o2[o] = 0.0f; ws[o] = 0.0f; }

#pragma unroll
    for (int r = 0; r < ROWS + 2 * RR; ++r) {                 // 18 neighbor rows
        const int   ny   = y0 + r - RR;
        const int   nyc  = ny < 0 ? 0 : (ny > HH - 1 ? HH - 1 : ny);
        const float rowf = ((unsigned)ny < (unsigned)HH) ? 1.0f : 0.0f;
        const int   rowoff = nyc * WW;
#pragma unroll
        for (int j = 0; j < KS; ++j) {                        // 11 neighbor cols
            const int   ni = rowoff + nxc[j];
            const float w  = pw[ni];
            const float i0 = img0[ni];
            const float i1 = img1[ni];
            const float i2 = img2[ni];

            const float denom = fmaf(2.0f * w, w, EPS_F);
            const float a  = -NLOG2E * __builtin_amdgcn_rcpf(denom);
            const float t  = exp2f(a);                        // t = exp(-1/(2w^2+eps))
            const float t2 = t * t, t4 = t2 * t2, t8 = t4 * t4;
            const float E1 = t, E4 = t4, E9 = t8 * t, E16 = t8 * t8, E25 = E16 * E9;

            const int jj = (j - RR) * (j - RR);               // constexpr after unroll
            float cj = jj == 0 ? 1.0f : jj == 1 ? E1 : jj == 4 ? E4
                     : jj == 9 ? E9 : jj == 16 ? E16 : E25;
            cj *= rowf * colf[j];                             // border mask (mv)

#pragma unroll
            for (int o = 0; o < ROWS; ++o) {                  // CONSTANT bounds
                const int iv = r - RR - o;                    // constexpr after unroll
                if (iv >= -RR && iv <= RR) {                  // constexpr guard
                    const int ii = iv * iv;
                    const float wi = ii == 0 ? 1.0f : ii == 1 ? E1 : ii == 4 ? E4
                                   : ii == 9 ? E9 : ii == 16 ? E16 : E25;
                    const float k = cj * wi;
                    ws[o] += k;
                    o0[o] = fmaf(i0, k, o0[o]);
                    o1[o] = fmaf(i1, k, o1[o]);
                    o2[o] = fmaf(i2, k, o2[o]);
                }
            }
        }
    }

#pragma unroll
    for (int o = 0; o < ROWS; ++o) {
        const float s = ws[o];                                // >= 1 (center tap = 1)
        float inv = __builtin_amdgcn_rcpf(s);
        inv = inv * (2.0f - s * inv);                         // Newton: ~1e-7 rel
        const int oi = (y0 + o) * WW + x;
        outb[oi]               = o0[o] * inv;
        outb[HH * WW + oi]     = o1[o] * inv;
        outb[2 * HH * WW + oi] = o2[o] * inv;
    }
}

extern "C" void kernel_launch(void* const* d_in, const int* in_sizes, int n_in,
                              void* d_out, int out_size, void* d_ws, size_t ws_size,
                              hipStream_t stream) {
    const float* image = (const float*)d_in[0];
    const float* psf   = (const float*)d_in[1];
    float* out = (float*)d_out;

    dim3 block(64, 4, 1);
    dim3 grid(WW / 64, HH / 32, 4);   // 512 blocks, 2048 waves
    gauss_psf_kernel<<<grid, block, 0, stream>>>(image, psf, out);
}

// Round 4
// 612.624 us; speedup vs baseline: 1.4215x; 1.4215x over previous
//
#include <hip/hip_runtime.h>

#define HH 512
#define WW 512
#define RR 5
#define KS 11
#define EPS_F 1e-5f
#define NLOG2E 1.44269504088896340736f
#define ROWS 4           // output rows per thread
#define TW 64            // tile width  (blockDim.x)
#define TH 16            // tile height (blockDim.y * ROWS)
#define LW (TW + 2*RR)   // 74 LDS tile width
#define LH (TH + 2*RR)   // 26 LDS tile height

// One dispatch. Block = (64,4), computes a 64x16 output tile for all 3 channels.
// Phase 1: cooperative LDS fill of masked t = exp(-1/(2w^2+eps)) (0 outside the
//   image). Removes the separate prepass launch AND all transcendentals/clamps/
//   masks from the hot loop: k(i,j) = t^{j^2} * t^{i^2}; masked t=0 makes every
//   OOB tap weight 0 automatically (center tap i=j=0 is always in-bounds).
// Phase 2: each thread accumulates a 4-row output column over the 15x11
//   neighbor window. Per neighbor: 1 ds_read + 3 image loads + 6 muls (powers
//   t^{m^2} by repeated squaring); per tap: 1 mul + 4 FMA, all accumulator
//   indexing compile-time (R2 lesson). sched_barrier(0) after each neighbor
//   row stops the scheduler hoisting loads across rows (R3 spill lesson).
__global__ __launch_bounds__(256) void gauss_psf_kernel(const float* __restrict__ image,
                                                        const float* __restrict__ psf,
                                                        float* __restrict__ out) {
    __shared__ float tt[LH * LW];

    const int tx  = threadIdx.x;           // 0..63
    const int ty  = threadIdx.y;           // 0..3
    const int tid = ty * 64 + tx;
    const int bx0 = blockIdx.x * TW;
    const int by0 = blockIdx.y * TH;
    const int b   = blockIdx.z;

    const float* pw = psf + (size_t)b * HH * WW;

    // ---- Phase 1: masked-t tile (26x74 = 1924 values, 8 passes of 256) ----
    for (int idx = tid; idx < LH * LW; idx += 256) {
        const int row = idx / LW, col = idx - row * LW;
        const int gy = by0 - RR + row, gx = bx0 - RR + col;
        const bool in = ((unsigned)gy < (unsigned)HH) && ((unsigned)gx < (unsigned)WW);
        const int cy = gy < 0 ? 0 : (gy > HH - 1 ? HH - 1 : gy);
        const int cx = gx < 0 ? 0 : (gx > WW - 1 ? WW - 1 : gx);
        const float w = pw[cy * WW + cx];
        const float a = -NLOG2E * __builtin_amdgcn_rcpf(fmaf(2.0f * w, w, EPS_F));
        const float t = __builtin_amdgcn_exp2f(a);   // exp(-1/(2w^2+eps))
        tt[idx] = in ? t : 0.0f;
    }
    __syncthreads();

    // ---- Phase 2: accumulate ----
    const int x  = bx0 + tx;
    const int y0 = by0 + ty * ROWS;
    const float* img0 = image + (size_t)b * 3 * HH * WW;
    const float* img1 = img0 + HH * WW;
    const float* img2 = img0 + 2 * HH * WW;
    float*       outb = out + (size_t)b * 3 * HH * WW;

    int nxc[KS];                                     // clamped neighbor columns
#pragma unroll
    for (int j = 0; j < KS; ++j) {
        const int nx = x + j - RR;
        nxc[j] = nx < 0 ? 0 : (nx > WW - 1 ? WW - 1 : nx);
    }

    float o0[ROWS], o1[ROWS], o2[ROWS], ws[ROWS];
#pragma unroll
    for (int o = 0; o < ROWS; ++o) { o0[o] = o1[o] = o2[o] = 0.0f; ws[o] = 0.0f; }

#pragma unroll
    for (int r = 0; r < ROWS + 2 * RR; ++r) {        // 14 neighbor rows
        const float* trow = &tt[(ty * ROWS + r) * LW + tx];
        int ny = y0 + r - RR;
        ny = ny < 0 ? 0 : (ny > HH - 1 ? HH - 1 : ny);
        const int rowoff = ny * WW;
#pragma unroll
        for (int j = 0; j < KS; ++j) {               // 11 neighbor cols
            const float t  = trow[j];                // ds_read, const offset
            const int   ni = rowoff + nxc[j];
            const float i0 = img0[ni];
            const float i1 = img1[ni];
            const float i2 = img2[ni];

            const float t2 = t * t, t4 = t2 * t2, t8 = t4 * t4;
            const float E1 = t, E4 = t4, E9 = t8 * t, E16 = t8 * t8, E25 = E16 * E9;

            const int jj = (j - RR) * (j - RR);      // constexpr after unroll
            const float cj = jj == 0 ? 1.0f : jj == 1 ? E1 : jj == 4 ? E4
                           : jj == 9 ? E9 : jj == 16 ? E16 : E25;

#pragma unroll
            for (int o = 0; o < ROWS; ++o) {         // constant bounds
                const int iv = r - RR - o;           // constexpr after unroll
                if (iv * iv <= RR * RR) {            // constexpr guard
                    const int ii = iv * iv;
                    const float wi = ii == 0 ? 1.0f : ii == 1 ? E1 : ii == 4 ? E4
                                   : ii == 9 ? E9 : ii == 16 ? E16 : E25;
                    const float k = cj * wi;
                    ws[o] += k;
                    o0[o] = fmaf(i0, k, o0[o]);
                    o1[o] = fmaf(i1, k, o1[o]);
                    o2[o] = fmaf(i2, k, o2[o]);
                }
            }
        }
        __builtin_amdgcn_sched_barrier(0);           // contain pressure per row
    }

#pragma unroll
    for (int o = 0; o < ROWS; ++o) {
        const float s = ws[o];                       // >= 1 (center tap = 1)
        float inv = __builtin_amdgcn_rcpf(s);
        inv = inv * (2.0f - s * inv);                // Newton: ~1e-7 rel
        const int oi = (y0 + o) * WW + x;
        outb[oi]               = o0[o] * inv;
        outb[HH * WW + oi]     = o1[o] * inv;
        outb[2 * HH * WW + oi] = o2[o] * inv;
    }
}

extern "C" void kernel_launch(void* const* d_in, const int* in_sizes, int n_in,
                              void* d_out, int out_size, void* d_ws, size_t ws_size,
                              hipStream_t stream) {
    const float* image = (const float*)d_in[0];
    const float* psf   = (const float*)d_in[1];
    float* out = (float*)d_out;

    dim3 block(64, 4, 1);
    dim3 grid(WW / TW, HH / TH, 4);   // 8 x 32 x 4 = 1024 blocks
    gauss_psf_kernel<<<grid, block, 0, stream>>>(image, psf, out);
}

// Round 5
// 112.567 us; speedup vs baseline: 7.7360x; 5.4423x over previous
//
#include <hip/hip_runtime.h>

#define HH 512
#define WW 512
#define RR 5
#define KS 11
#define EPS_F 1e-5f
#define NLOG2E 1.44269504088896340736f
#define TW 64            // tile width  (blockDim.x)
#define TH 4             // tile height (blockDim.y), ROWS=1 per thread
#define LW (TW + 2*RR)   // 74
#define LH (TH + 2*RR)   // 14

// R5: R1's proven codegen shape (1 px/thread, 4 accumulators, VGPR~28, no
// spill) with the VALU fat removed:
//  - LDS tile of masked t = exp(-1/(2w^2+eps)) (0 outside image). One raw
//    v_exp_f32 + v_rcp per NEIGHBOR per BLOCK instead of per tap; hot loop
//    has no transcendentals, no masks, no weight-side clamps.
//  - tap weight t^(i^2+j^2) via compile-time binary decomposition (~7 muls).
//  - OOB taps: t=0 => t^e=0 for e>0; the only e=0 tap is the center, always
//    in-bounds. Image reads use clamped indices (weight 0 kills them).
// R2 lesson: accumulators scalar, all indexing compile-time.
// R3/R4 lesson: do NOT coarsen; big unrolled bodies + many accumulators spill.
__global__ __launch_bounds__(256) void gauss_psf_kernel(const float* __restrict__ image,
                                                        const float* __restrict__ psf,
                                                        float* __restrict__ out) {
    __shared__ float tt[LH * LW];   // 1036 floats = 4.1 KB

    const int tx  = threadIdx.x;           // 0..63
    const int ty  = threadIdx.y;           // 0..3
    const int tid = ty * 64 + tx;
    const int bx0 = blockIdx.x * TW;
    const int by0 = blockIdx.y * TH;
    const int b   = blockIdx.z;

    const float* pw = psf + (size_t)b * HH * WW;

    // ---- Phase 1: masked-t halo tile (5 passes of 256 threads) ----
#pragma unroll
    for (int base = 0; base < LH * LW; base += 256) {
        const int idx = base + tid;
        if (idx < LH * LW) {
            const int row = idx / LW, col = idx - row * LW;
            const int gy = by0 - RR + row, gx = bx0 - RR + col;
            const bool in = ((unsigned)gy < (unsigned)HH) && ((unsigned)gx < (unsigned)WW);
            const int cy = gy < 0 ? 0 : (gy > HH - 1 ? HH - 1 : gy);
            const int cx = gx < 0 ? 0 : (gx > WW - 1 ? WW - 1 : gx);
            const float w = pw[cy * WW + cx];
            const float a = -NLOG2E * __builtin_amdgcn_rcpf(fmaf(2.0f * w, w, EPS_F));
            // a in [-8.03, -0.066]: raw v_exp_f32 is safe (no denorm fixup path)
            tt[idx] = in ? __builtin_amdgcn_exp2f(a) : 0.0f;
        }
    }
    __syncthreads();

    // ---- Phase 2: 121-tap accumulation, 1 pixel/thread ----
    const int x = bx0 + tx;
    const int y = by0 + ty;

    const float* img0 = image + (size_t)b * 3 * HH * WW;
    const float* img1 = img0 + HH * WW;
    const float* img2 = img0 + 2 * HH * WW;

    int nxc[KS];                            // clamped neighbor columns (hoisted)
#pragma unroll
    for (int j = 0; j < KS; ++j) {
        const int nx = x + j - RR;
        nxc[j] = nx < 0 ? 0 : (nx > WW - 1 ? WW - 1 : nx);
    }

    float o0 = 0.0f, o1 = 0.0f, o2 = 0.0f, ws = 0.0f;
    const float* tbase = &tt[ty * LW + tx]; // (r,j) become constant ds offsets

#pragma unroll
    for (int r = 0; r < KS; ++r) {
        int ny = y + r - RR;
        ny = ny < 0 ? 0 : (ny > HH - 1 ? HH - 1 : ny);
        const int rowoff = ny * WW;
        const int ii = (r - RR) * (r - RR);             // constexpr
#pragma unroll
        for (int j = 0; j < KS; ++j) {
            const float t  = tbase[r * LW + j];         // ds_read, const offset
            const int   ni = rowoff + nxc[j];
            const float i0 = img0[ni];
            const float i1 = img1[ni];
            const float i2 = img2[ni];

            const int e = ii + (j - RR) * (j - RR);     // 0..50, constexpr
            // t^e, binary decomposition; unused squarings DCE'd per tap
            const float T1 = t, T2 = T1 * T1, T4 = T2 * T2,
                        T8 = T4 * T4, T16 = T8 * T8, T32 = T16 * T16;
            float p = 1.0f;
            if (e & 1)  p *= T1;
            if (e & 2)  p *= T2;
            if (e & 4)  p *= T4;
            if (e & 8)  p *= T8;
            if (e & 16) p *= T16;
            if (e & 32) p *= T32;

            ws += p;
            o0 = fmaf(i0, p, o0);
            o1 = fmaf(i1, p, o1);
            o2 = fmaf(i2, p, o2);
        }
    }

    float inv = __builtin_amdgcn_rcpf(ws);              // ws >= 1 (center tap)
    inv = inv * (2.0f - ws * inv);                      // Newton: ~1e-7 rel
    const int oi = y * WW + x;
    float* outb = out + (size_t)b * 3 * HH * WW;
    outb[oi]               = o0 * inv;
    outb[HH * WW + oi]     = o1 * inv;
    outb[2 * HH * WW + oi] = o2 * inv;
}

extern "C" void kernel_launch(void* const* d_in, const int* in_sizes, int n_in,
                              void* d_out, int out_size, void* d_ws, size_t ws_size,
                              hipStream_t stream) {
    const float* image = (const float*)d_in[0];
    const float* psf   = (const float*)d_in[1];
    float* out = (float*)d_out;

    dim3 block(64, 4, 1);
    dim3 grid(WW / TW, HH / TH, 4);   // 8 x 128 x 4 = 4096 blocks, 16384 waves
    gauss_psf_kernel<<<grid, block, 0, stream>>>(image, psf, out);
}